// Round 1
// baseline (1325.095 us; speedup 1.0000x reference)
//
#include <hip/hip_runtime.h>
#include <hip/hip_bf16.h>
#include <cstdint>

#define HIDDEN   2048
#define HV       32
#define HK       16
#define DK       128
#define DV       128
#define KEY_DIM  2048
#define VAL_DIM  4096
#define CONV_DIM 8192
#define NTOK     2048   // B*S
#define SEQ      1024
#define N1       12288  // 2*KEY_DIM + VAL_DIM (qkv ++ z fused GEMM)

typedef __attribute__((ext_vector_type(4))) float f4_t;
typedef __attribute__((ext_vector_type(8))) short bf8_t;
typedef __attribute__((ext_vector_type(4))) unsigned short u16x4;
typedef __attribute__((ext_vector_type(8))) unsigned short u16x8;

__device__ __forceinline__ unsigned short f2bf(float f) {
    union { float f; uint32_t u; } a; a.f = f;
    uint32_t u = a.u;
    return (unsigned short)((u + 0x7fff + ((u >> 16) & 1)) >> 16);
}

// ---------------- cast hs -> bf16 ----------------
__global__ __launch_bounds__(256) void k_cast_hs(const float* __restrict__ hs,
                                                 unsigned short* __restrict__ out) {
    int i = blockIdx.x * 256 + threadIdx.x;  // float4 index
    f4_t v = ((const f4_t*)hs)[i];
    u16x4 o;
    o[0] = f2bf(v[0]); o[1] = f2bf(v[1]); o[2] = f2bf(v[2]); o[3] = f2bf(v[3]);
    ((u16x4*)out)[i] = o;
}

// ---------------- transpose+cast: W1t[n][k] = {w_qkv|w_z}[k][n] ----------------
__global__ __launch_bounds__(256) void k_trans_w1(const float* __restrict__ w_qkv,
                                                  const float* __restrict__ w_z,
                                                  unsigned short* __restrict__ w1t) {
    __shared__ float tile[32][33];
    int tx = threadIdx.x & 31, ty = threadIdx.x >> 5;
    int n0 = blockIdx.x * 32, k0 = blockIdx.y * 32;
    int n = n0 + tx;
#pragma unroll
    for (int i = 0; i < 4; i++) {
        int k = k0 + ty + i * 8;
        float v = (n < CONV_DIM) ? w_qkv[(size_t)k * CONV_DIM + n]
                                 : w_z[(size_t)k * VAL_DIM + (n - CONV_DIM)];
        tile[ty + i * 8][tx] = v;
    }
    __syncthreads();
#pragma unroll
    for (int i = 0; i < 4; i++)
        w1t[(size_t)(n0 + ty + i * 8) * HIDDEN + k0 + tx] = f2bf(tile[tx][ty + i * 8]);
}

// generic: dst[n*K+k] = src[k*N+n]   (src [K,N] fp32 -> dst [N,K] bf16)
__global__ __launch_bounds__(256) void k_trans(const float* __restrict__ src,
                                               unsigned short* __restrict__ dst,
                                               int K, int N) {
    __shared__ float tile[32][33];
    int tx = threadIdx.x & 31, ty = threadIdx.x >> 5;
    int n0 = blockIdx.x * 32, k0 = blockIdx.y * 32;
#pragma unroll
    for (int i = 0; i < 4; i++)
        tile[ty + i * 8][tx] = src[(size_t)(k0 + ty + i * 8) * N + n0 + tx];
    __syncthreads();
#pragma unroll
    for (int i = 0; i < 4; i++)
        dst[(size_t)(n0 + ty + i * 8) * K + k0 + tx] = f2bf(tile[tx][ty + i * 8]);
}

// ---------------- bf16 MFMA GEMM:  C[M,N] = A[M,K] * B[N,K]^T ----------------
__global__ __launch_bounds__(256, 2) void k_gemm_bt(const unsigned short* __restrict__ A,
                                                    const unsigned short* __restrict__ B,
                                                    float* __restrict__ C, int K, int N) {
    __shared__ unsigned short lA[128 * 32];
    __shared__ unsigned short lB[128 * 32];
    int tid = threadIdx.x;
    int wave = tid >> 6, lane = tid & 63;
    int m0 = blockIdx.x * 128, n0 = blockIdx.y * 128;
    int wm = wave & 1, wn = wave >> 1;
    f4_t acc[4][4];
#pragma unroll
    for (int i = 0; i < 4; i++)
#pragma unroll
        for (int j = 0; j < 4; j++) acc[i][j] = (f4_t){0.f, 0.f, 0.f, 0.f};
    int srow = wave * 16 + (lane >> 2);
    int scol = (lane & 3) * 8;                 // element offset (8 bf16 = 16B)
    int quad = lane >> 4, lrow = lane & 15;

    for (int k0 = 0; k0 < K; k0 += 32) {
        const unsigned short* gA0 = A + (size_t)(m0 + srow) * K + k0 + scol;
        const unsigned short* gA1 = A + (size_t)(m0 + 64 + srow) * K + k0 + scol;
        const unsigned short* gB0 = B + (size_t)(n0 + srow) * K + k0 + scol;
        const unsigned short* gB1 = B + (size_t)(n0 + 64 + srow) * K + k0 + scol;
        __syncthreads();  // previous compute done before overwriting LDS
        __builtin_amdgcn_global_load_lds((const __attribute__((address_space(1))) void*)gA0,
            (__attribute__((address_space(3))) void*)(&lA[wave * 512]), 16, 0, 0);
        __builtin_amdgcn_global_load_lds((const __attribute__((address_space(1))) void*)gA1,
            (__attribute__((address_space(3))) void*)(&lA[2048 + wave * 512]), 16, 0, 0);
        __builtin_amdgcn_global_load_lds((const __attribute__((address_space(1))) void*)gB0,
            (__attribute__((address_space(3))) void*)(&lB[wave * 512]), 16, 0, 0);
        __builtin_amdgcn_global_load_lds((const __attribute__((address_space(1))) void*)gB1,
            (__attribute__((address_space(3))) void*)(&lB[2048 + wave * 512]), 16, 0, 0);
        __syncthreads();  // loads drained (vmcnt(0) before barrier)
        bf8_t af[4], bfv[4];
#pragma unroll
        for (int i = 0; i < 4; i++) {
            af[i]  = *(const bf8_t*)&lA[(wm * 64 + i * 16 + lrow) * 32 + quad * 8];
            bfv[i] = *(const bf8_t*)&lB[(wn * 64 + i * 16 + lrow) * 32 + quad * 8];
        }
#pragma unroll
        for (int i = 0; i < 4; i++)
#pragma unroll
            for (int j = 0; j < 4; j++)
                acc[i][j] = __builtin_amdgcn_mfma_f32_16x16x32_bf16(af[i], bfv[j], acc[i][j], 0, 0, 0);
    }
    // epilogue: C/D layout col=lane&15, row=(lane>>4)*4+reg
#pragma unroll
    for (int i = 0; i < 4; i++) {
        int row_b = m0 + wm * 64 + i * 16 + quad * 4;
#pragma unroll
        for (int j = 0; j < 4; j++) {
            int col = n0 + wn * 64 + j * 16 + lrow;
#pragma unroll
            for (int r = 0; r < 4; r++)
                C[(size_t)(row_b + r) * N + col] = acc[i][j][r];
        }
    }
}

// ---------------- beta / decay (fp32-exact path) ----------------
__global__ __launch_bounds__(256) void k_beta_g(const float* __restrict__ hs,
                                                const float* __restrict__ w_b,
                                                const float* __restrict__ w_a,
                                                const float* __restrict__ dt_bias,
                                                const float* __restrict__ A_log,
                                                float* __restrict__ beta,
                                                float* __restrict__ eg) {
    __shared__ float row[HIDDEN];
    __shared__ float part[256];
    int tok = blockIdx.x, t = threadIdx.x;
    for (int i = t; i < HIDDEN; i += 256) row[i] = hs[(size_t)tok * HIDDEN + i];
    __syncthreads();
    int out = t & 63, qtr = t >> 6;
    const float* w = (out < 32) ? w_b : w_a;
    int h = out & 31;
    float acc = 0.f;
    for (int k = qtr * 512; k < qtr * 512 + 512; k++) acc += row[k] * w[k * 32 + h];
    part[t] = acc;
    __syncthreads();
    if (t < 64) {
        float s = part[t] + part[t + 64] + part[t + 128] + part[t + 192];
        if (t < 32) {
            beta[tok * 32 + t] = 1.f / (1.f + expf(-s));
        } else {
            int hh = t - 32;
            float x = s + dt_bias[hh];
            float sp = (x > 20.f) ? x : log1pf(expf(x));
            eg[tok * 32 + hh] = expf(-expf(A_log[hh]) * sp);
        }
    }
}

// ---------------- conv halo save (race-free chunked in-place conv) ----------------
__global__ __launch_bounds__(256) void k_halo(const float* __restrict__ mixed,
                                              float* __restrict__ halo) {
    int id = blockIdx.x * 256 + threadIdx.x;  // 2*3*3*8192
    int c = id & 8191;
    int r = id >> 13;        // 0..17
    int tap = r % 3;
    int jm1 = (r / 3) % 3;
    int b = r / 9;
    int s = (jm1 + 1) * 256 - 1 - tap;
    halo[id] = mixed[(size_t)(b * SEQ + s) * N1 + c];
}

__global__ __launch_bounds__(256) void k_conv(float* __restrict__ mixed,
                                              const float* __restrict__ cw,
                                              const float* __restrict__ halo) {
    int id = blockIdx.x * 256 + threadIdx.x;  // 2*4*8192
    int c = id & 8191;
    int r = id >> 13;
    int chunk = r & 3, b = r >> 2;
    int s0 = chunk * 256;
    float w0 = cw[c * 4 + 0], w1 = cw[c * 4 + 1], w2 = cw[c * 4 + 2], w3 = cw[c * 4 + 3];
    float xm1, xm2, xm3;
    if (chunk == 0) {
        xm1 = xm2 = xm3 = 0.f;
    } else {
        const float* hp = halo + (size_t)(b * 3 + chunk - 1) * 3 * 8192;
        xm1 = hp[0 * 8192 + c]; xm2 = hp[1 * 8192 + c]; xm3 = hp[2 * 8192 + c];
    }
    float* col = mixed + (size_t)(b * SEQ + s0) * N1 + c;
    for (int s = 0; s < 256; s++) {
        float x = col[(size_t)s * N1];
        float y = w3 * x + w2 * xm1 + w1 * xm2 + w0 * xm3;
        y = y / (1.f + expf(-y));        // SiLU
        col[(size_t)s * N1] = y;
        xm3 = xm2; xm2 = xm1; xm1 = x;
    }
}

// ---------------- l2norm of q (with 1/sqrt(DK)) and k, in-place ----------------
__global__ __launch_bounds__(256) void k_l2norm(float* __restrict__ mixed) {
    int tok = blockIdx.x, t = threadIdx.x;
    int vec = t >> 3, ln = t & 7;  // 32 vectors of 128, 8 lanes x 16 elems
    int off = (vec < 16) ? vec * 128 : 2048 + (vec - 16) * 128;
    float* p = mixed + (size_t)tok * N1 + off + ln * 16;
    f4_t x0 = ((f4_t*)p)[0], x1 = ((f4_t*)p)[1], x2 = ((f4_t*)p)[2], x3 = ((f4_t*)p)[3];
    float ss = 0.f;
#pragma unroll
    for (int i = 0; i < 4; i++) ss += x0[i]*x0[i] + x1[i]*x1[i] + x2[i]*x2[i] + x3[i]*x3[i];
    ss += __shfl_xor(ss, 1); ss += __shfl_xor(ss, 2); ss += __shfl_xor(ss, 4);
    float sc = 1.f / sqrtf(ss + 1e-6f);
    if (vec < 16) sc *= 0.08838834764831845f;  // DK^-0.5
#pragma unroll
    for (int i = 0; i < 4; i++) { x0[i]*=sc; x1[i]*=sc; x2[i]*=sc; x3[i]*=sc; }
    ((f4_t*)p)[0] = x0; ((f4_t*)p)[1] = x1; ((f4_t*)p)[2] = x2; ((f4_t*)p)[3] = x3;
}

// ---------------- gated delta-rule scan ----------------
// grid 256 = (b,h,colgroup): each block 256 threads = 32 cols x 8 k-segments.
// Thread owns 16 state floats S[seg*16 .. seg*16+16) of column `col`.
union F16 { f4_t v[4]; float f[16]; };

__global__ __launch_bounds__(256, 1) void k_recur(const float* __restrict__ mixed,
                                                  const float* __restrict__ beta,
                                                  const float* __restrict__ eg,
                                                  float* __restrict__ o) {
    int blk = blockIdx.x;
    int cg = blk & 3, bh = blk >> 2;
    int h = bh & 31, b = bh >> 5;
    int hk = h >> 1;
    int t = threadIdx.x;
    int col = cg * 32 + (t >> 3);
    int seg = t & 7;
    const float* qbase = mixed + (size_t)(b * SEQ) * N1 + hk * 128 + seg * 16;
    const float* kbase = qbase + 2048;
    const float* vbase = mixed + (size_t)(b * SEQ) * N1 + 4096 + h * 128 + col;
    const float* gbase = eg + (size_t)(b * SEQ) * 32 + h;
    const float* bbase = beta + (size_t)(b * SEQ) * 32 + h;
    float* obase = o + (size_t)(b * SEQ) * 4096 + h * 128 + col;

    float S[16];
#pragma unroll
    for (int j = 0; j < 16; j++) S[j] = 0.f;

    F16 qc, kc;
    {
        const f4_t* qp = (const f4_t*)qbase;
        const f4_t* kp = (const f4_t*)kbase;
#pragma unroll
        for (int i = 0; i < 4; i++) { qc.v[i] = qp[i]; kc.v[i] = kp[i]; }
    }
    float vv = vbase[0], egs = gbase[0], bts = bbase[0];

    for (int s = 0; s < SEQ; s++) {
        int s1 = (s + 1 < SEQ) ? s + 1 : SEQ - 1;
        // prefetch next step
        F16 qn, kn;
        const f4_t* qp = (const f4_t*)(qbase + (size_t)s1 * N1);
        const f4_t* kp = (const f4_t*)(kbase + (size_t)s1 * N1);
#pragma unroll
        for (int i = 0; i < 4; i++) { qn.v[i] = qp[i]; kn.v[i] = kp[i]; }
        float vv1 = vbase[(size_t)s1 * N1];
        float egs1 = gbase[(size_t)s1 * 32];
        float bts1 = bbase[(size_t)s1 * 32];

        // pass 1: decay + k.S readout
        float acc = 0.f;
#pragma unroll
        for (int j = 0; j < 16; j++) { S[j] *= egs; acc = fmaf(kc.f[j], S[j], acc); }
        acc += __shfl_xor(acc, 1); acc += __shfl_xor(acc, 2); acc += __shfl_xor(acc, 4);
        float delta = (vv - acc) * bts;
        // pass 2: rank-1 write + q.S readout
        float oa = 0.f;
#pragma unroll
        for (int j = 0; j < 16; j++) { S[j] = fmaf(kc.f[j], delta, S[j]); oa = fmaf(qc.f[j], S[j], oa); }
        oa += __shfl_xor(oa, 1); oa += __shfl_xor(oa, 2); oa += __shfl_xor(oa, 4);
        if (seg == 0) obase[(size_t)s * 4096] = oa;

        qc = qn; kc = kn; vv = vv1; egs = egs1; bts = bts1;
    }
}

// ---------------- gated RMSNorm -> bf16 ----------------
__global__ __launch_bounds__(256) void k_gnorm(const float* __restrict__ o,
                                               const float* __restrict__ mixed,
                                               const float* __restrict__ norm_w,
                                               unsigned short* __restrict__ on) {
    int tok = blockIdx.x, t = threadIdx.x;
    int hh = t >> 3, ln = t & 7;
    const f4_t* op = (const f4_t*)(o + (size_t)tok * 4096 + hh * 128 + ln * 16);
    const f4_t* zp = (const f4_t*)(mixed + (size_t)tok * N1 + 8192 + hh * 128 + ln * 16);
    float og[16];
    float ss = 0.f;
#pragma unroll
    for (int i = 0; i < 4; i++) {
        f4_t ov = op[i], zv = zp[i];
#pragma unroll
        for (int j = 0; j < 4; j++) {
            float z = zv[j];
            float g = ov[j] * (z / (1.f + expf(-z)));
            og[i * 4 + j] = g;
            ss += g * g;
        }
    }
    ss += __shfl_xor(ss, 1); ss += __shfl_xor(ss, 2); ss += __shfl_xor(ss, 4);
    float r = 1.f / sqrtf(ss * (1.f / 128.f) + 1e-6f);
    unsigned short* onp = on + (size_t)tok * 4096 + hh * 128 + ln * 16;
    u16x8 a, bb;
#pragma unroll
    for (int j = 0; j < 8; j++) a[j] = f2bf(og[j] * r * norm_w[ln * 16 + j]);
#pragma unroll
    for (int j = 0; j < 8; j++) bb[j] = f2bf(og[8 + j] * r * norm_w[ln * 16 + 8 + j]);
    ((u16x8*)onp)[0] = a;
    ((u16x8*)onp)[1] = bb;
}

extern "C" void kernel_launch(void* const* d_in, const int* in_sizes, int n_in,
                              void* d_out, int out_size, void* d_ws, size_t ws_size,
                              hipStream_t stream) {
    const float* hs      = (const float*)d_in[0];
    const float* conv_w  = (const float*)d_in[1];
    const float* w_qkv   = (const float*)d_in[2];
    const float* w_z     = (const float*)d_in[3];
    const float* w_b     = (const float*)d_in[4];
    const float* w_a     = (const float*)d_in[5];
    const float* w_out   = (const float*)d_in[6];
    const float* dt_bias = (const float*)d_in[7];
    const float* A_log   = (const float*)d_in[8];
    const float* norm_w  = (const float*)d_in[9];
    float* out = (float*)d_out;

    char* ws = (char*)d_ws;
    unsigned short* hs_bf = (unsigned short*)ws; ws += (size_t)NTOK * HIDDEN * 2;   // 8 MB
    unsigned short* w1t   = (unsigned short*)ws; ws += (size_t)N1 * HIDDEN * 2;     // 48 MB
    unsigned short* wot   = (unsigned short*)ws; ws += (size_t)HIDDEN * VAL_DIM * 2;// 16 MB
    float* mixed          = (float*)ws;          ws += (size_t)NTOK * N1 * 4;       // 96 MB
    float* beta           = (float*)ws;          ws += (size_t)NTOK * 32 * 4;
    float* eg             = (float*)ws;          ws += (size_t)NTOK * 32 * 4;
    float* halo           = (float*)ws;          ws += (size_t)2 * 3 * 3 * 8192 * 4;
    float* o_buf          = (float*)ws;          ws += (size_t)NTOK * VAL_DIM * 4;  // 32 MB
    unsigned short* on_bf = (unsigned short*)ws; ws += (size_t)NTOK * VAL_DIM * 2;  // 16 MB
    // total ~217 MB

    k_cast_hs<<<dim3(NTOK * HIDDEN / 4 / 256), 256, 0, stream>>>(hs, hs_bf);
    k_trans_w1<<<dim3(N1 / 32, HIDDEN / 32), 256, 0, stream>>>(w_qkv, w_z, w1t);
    k_trans<<<dim3(HIDDEN / 32, VAL_DIM / 32), 256, 0, stream>>>(w_out, wot, VAL_DIM, HIDDEN);
    k_gemm_bt<<<dim3(NTOK / 128, N1 / 128), 256, 0, stream>>>(hs_bf, w1t, mixed, HIDDEN, N1);
    k_beta_g<<<dim3(NTOK), 256, 0, stream>>>(hs, w_b, w_a, dt_bias, A_log, beta, eg);
    k_halo<<<dim3(2 * 3 * 3 * 8192 / 256), 256, 0, stream>>>(mixed, halo);
    k_conv<<<dim3(2 * 4 * 8192 / 256), 256, 0, stream>>>(mixed, conv_w, halo);
    k_l2norm<<<dim3(NTOK), 256, 0, stream>>>(mixed);
    k_recur<<<dim3(256), 256, 0, stream>>>(mixed, beta, eg, o_buf);
    k_gnorm<<<dim3(NTOK), 256, 0, stream>>>(o_buf, mixed, norm_w, on_bf);
    k_gemm_bt<<<dim3(NTOK / 128, HIDDEN / 128), 256, 0, stream>>>(on_bf, wot, out, VAL_DIM, HIDDEN);
}

// Round 2
// 1236.138 us; speedup vs baseline: 1.0720x; 1.0720x over previous
//
#include <hip/hip_runtime.h>
#include <hip/hip_bf16.h>
#include <cstdint>

#define HIDDEN   2048
#define HV       32
#define HK       16
#define DK       128
#define DV       128
#define KEY_DIM  2048
#define VAL_DIM  4096
#define CONV_DIM 8192
#define NTOK     2048   // B*S
#define SEQ      1024
#define N1       12288  // 2*KEY_DIM + VAL_DIM (qkv ++ z fused GEMM)

typedef __attribute__((ext_vector_type(4))) float f4_t;
typedef __attribute__((ext_vector_type(8))) short bf8_t;
typedef __attribute__((ext_vector_type(4))) unsigned short u16x4;
typedef __attribute__((ext_vector_type(8))) unsigned short u16x8;

__device__ __forceinline__ unsigned short f2bf(float f) {
    union { float f; uint32_t u; } a; a.f = f;
    uint32_t u = a.u;
    return (unsigned short)((u + 0x7fff + ((u >> 16) & 1)) >> 16);
}

// ---------------- cast hs -> bf16 ----------------
__global__ __launch_bounds__(256) void k_cast_hs(const float* __restrict__ hs,
                                                 unsigned short* __restrict__ out) {
    int i = blockIdx.x * 256 + threadIdx.x;  // float4 index
    f4_t v = ((const f4_t*)hs)[i];
    u16x4 o;
    o[0] = f2bf(v[0]); o[1] = f2bf(v[1]); o[2] = f2bf(v[2]); o[3] = f2bf(v[3]);
    ((u16x4*)out)[i] = o;
}

// ---------------- transpose+cast: W1t[n][k] = {w_qkv|w_z}[k][n] ----------------
__global__ __launch_bounds__(256) void k_trans_w1(const float* __restrict__ w_qkv,
                                                  const float* __restrict__ w_z,
                                                  unsigned short* __restrict__ w1t) {
    __shared__ float tile[32][33];
    int tx = threadIdx.x & 31, ty = threadIdx.x >> 5;
    int n0 = blockIdx.x * 32, k0 = blockIdx.y * 32;
    int n = n0 + tx;
#pragma unroll
    for (int i = 0; i < 4; i++) {
        int k = k0 + ty + i * 8;
        float v = (n < CONV_DIM) ? w_qkv[(size_t)k * CONV_DIM + n]
                                 : w_z[(size_t)k * VAL_DIM + (n - CONV_DIM)];
        tile[ty + i * 8][tx] = v;
    }
    __syncthreads();
#pragma unroll
    for (int i = 0; i < 4; i++)
        w1t[(size_t)(n0 + ty + i * 8) * HIDDEN + k0 + tx] = f2bf(tile[tx][ty + i * 8]);
}

// generic: dst[n*K+k] = src[k*N+n]   (src [K,N] fp32 -> dst [N,K] bf16)
__global__ __launch_bounds__(256) void k_trans(const float* __restrict__ src,
                                               unsigned short* __restrict__ dst,
                                               int K, int N) {
    __shared__ float tile[32][33];
    int tx = threadIdx.x & 31, ty = threadIdx.x >> 5;
    int n0 = blockIdx.x * 32, k0 = blockIdx.y * 32;
#pragma unroll
    for (int i = 0; i < 4; i++)
        tile[ty + i * 8][tx] = src[(size_t)(k0 + ty + i * 8) * N + n0 + tx];
    __syncthreads();
#pragma unroll
    for (int i = 0; i < 4; i++)
        dst[(size_t)(n0 + ty + i * 8) * K + k0 + tx] = f2bf(tile[tx][ty + i * 8]);
}

// ---------------- bf16 MFMA GEMM:  C[M,N] = A[M,K] * B[N,K]^T ----------------
__global__ __launch_bounds__(256, 2) void k_gemm_bt(const unsigned short* __restrict__ A,
                                                    const unsigned short* __restrict__ B,
                                                    float* __restrict__ C, int K, int N) {
    __shared__ unsigned short lA[128 * 32];
    __shared__ unsigned short lB[128 * 32];
    int tid = threadIdx.x;
    int wave = tid >> 6, lane = tid & 63;
    int m0 = blockIdx.x * 128, n0 = blockIdx.y * 128;
    int wm = wave & 1, wn = wave >> 1;
    f4_t acc[4][4];
#pragma unroll
    for (int i = 0; i < 4; i++)
#pragma unroll
        for (int j = 0; j < 4; j++) acc[i][j] = (f4_t){0.f, 0.f, 0.f, 0.f};
    int srow = wave * 16 + (lane >> 2);
    int scol = (lane & 3) * 8;                 // element offset (8 bf16 = 16B)
    int quad = lane >> 4, lrow = lane & 15;

    for (int k0 = 0; k0 < K; k0 += 32) {
        const unsigned short* gA0 = A + (size_t)(m0 + srow) * K + k0 + scol;
        const unsigned short* gA1 = A + (size_t)(m0 + 64 + srow) * K + k0 + scol;
        const unsigned short* gB0 = B + (size_t)(n0 + srow) * K + k0 + scol;
        const unsigned short* gB1 = B + (size_t)(n0 + 64 + srow) * K + k0 + scol;
        __syncthreads();  // previous compute done before overwriting LDS
        __builtin_amdgcn_global_load_lds((const __attribute__((address_space(1))) void*)gA0,
            (__attribute__((address_space(3))) void*)(&lA[wave * 512]), 16, 0, 0);
        __builtin_amdgcn_global_load_lds((const __attribute__((address_space(1))) void*)gA1,
            (__attribute__((address_space(3))) void*)(&lA[2048 + wave * 512]), 16, 0, 0);
        __builtin_amdgcn_global_load_lds((const __attribute__((address_space(1))) void*)gB0,
            (__attribute__((address_space(3))) void*)(&lB[wave * 512]), 16, 0, 0);
        __builtin_amdgcn_global_load_lds((const __attribute__((address_space(1))) void*)gB1,
            (__attribute__((address_space(3))) void*)(&lB[2048 + wave * 512]), 16, 0, 0);
        __syncthreads();  // loads drained (vmcnt(0) before barrier)
        bf8_t af[4], bfv[4];
#pragma unroll
        for (int i = 0; i < 4; i++) {
            af[i]  = *(const bf8_t*)&lA[(wm * 64 + i * 16 + lrow) * 32 + quad * 8];
            bfv[i] = *(const bf8_t*)&lB[(wn * 64 + i * 16 + lrow) * 32 + quad * 8];
        }
#pragma unroll
        for (int i = 0; i < 4; i++)
#pragma unroll
            for (int j = 0; j < 4; j++)
                acc[i][j] = __builtin_amdgcn_mfma_f32_16x16x32_bf16(af[i], bfv[j], acc[i][j], 0, 0, 0);
    }
    // epilogue: C/D layout col=lane&15, row=(lane>>4)*4+reg
#pragma unroll
    for (int i = 0; i < 4; i++) {
        int row_b = m0 + wm * 64 + i * 16 + quad * 4;
#pragma unroll
        for (int j = 0; j < 4; j++) {
            int col = n0 + wn * 64 + j * 16 + lrow;
#pragma unroll
            for (int r = 0; r < 4; r++)
                C[(size_t)(row_b + r) * N + col] = acc[i][j][r];
        }
    }
}

// ---------------- beta / decay (fp32-exact path) ----------------
__global__ __launch_bounds__(256) void k_beta_g(const float* __restrict__ hs,
                                                const float* __restrict__ w_b,
                                                const float* __restrict__ w_a,
                                                const float* __restrict__ dt_bias,
                                                const float* __restrict__ A_log,
                                                float* __restrict__ beta,
                                                float* __restrict__ eg) {
    __shared__ float row[HIDDEN];
    __shared__ float part[256];
    int tok = blockIdx.x, t = threadIdx.x;
    for (int i = t; i < HIDDEN; i += 256) row[i] = hs[(size_t)tok * HIDDEN + i];
    __syncthreads();
    int out = t & 63, qtr = t >> 6;
    const float* w = (out < 32) ? w_b : w_a;
    int h = out & 31;
    float acc = 0.f;
    for (int k = qtr * 512; k < qtr * 512 + 512; k++) acc += row[k] * w[k * 32 + h];
    part[t] = acc;
    __syncthreads();
    if (t < 64) {
        float s = part[t] + part[t + 64] + part[t + 128] + part[t + 192];
        if (t < 32) {
            beta[tok * 32 + t] = 1.f / (1.f + expf(-s));
        } else {
            int hh = t - 32;
            float x = s + dt_bias[hh];
            float sp = (x > 20.f) ? x : log1pf(expf(x));
            eg[tok * 32 + hh] = expf(-expf(A_log[hh]) * sp);
        }
    }
}

// ---------------- conv halo save (race-free chunked in-place conv) ----------------
#define CCH 32                    // conv chunk length
#define NCH (SEQ / CCH)           // 32 chunks per batch
__global__ __launch_bounds__(256) void k_halo(const float* __restrict__ mixed,
                                              float* __restrict__ halo) {
    int id = blockIdx.x * 256 + threadIdx.x;  // 2*(NCH-1)*3*8192
    int c = id & 8191;
    int r = id >> 13;            // 0 .. 2*31*3-1
    int tap = r % 3;
    int ck = (r / 3) % (NCH - 1);
    int b = r / (3 * (NCH - 1));
    int s = (ck + 1) * CCH - 1 - tap;
    halo[id] = mixed[(size_t)(b * SEQ + s) * N1 + c];
}

__global__ __launch_bounds__(256) void k_conv(float* __restrict__ mixed,
                                              const float* __restrict__ cw,
                                              const float* __restrict__ halo) {
    int id = blockIdx.x * 256 + threadIdx.x;  // 2*NCH*8192
    int c = id & 8191;
    int r = id >> 13;
    int chunk = r & (NCH - 1), b = r >> 5;
    int s0 = chunk * CCH;
    float w0 = cw[c * 4 + 0], w1 = cw[c * 4 + 1], w2 = cw[c * 4 + 2], w3 = cw[c * 4 + 3];
    float xm1, xm2, xm3;
    if (chunk == 0) {
        xm1 = xm2 = xm3 = 0.f;
    } else {
        const float* hp = halo + (size_t)(b * (NCH - 1) + chunk - 1) * 3 * 8192;
        xm1 = hp[0 * 8192 + c]; xm2 = hp[1 * 8192 + c]; xm3 = hp[2 * 8192 + c];
    }
    float* col = mixed + (size_t)(b * SEQ + s0) * N1 + c;
#pragma unroll
    for (int s = 0; s < CCH; s++) {
        float x = col[(size_t)s * N1];
        float y = w3 * x + w2 * xm1 + w1 * xm2 + w0 * xm3;
        y = y / (1.f + expf(-y));        // SiLU
        col[(size_t)s * N1] = y;
        xm3 = xm2; xm2 = xm1; xm1 = x;
    }
}

// ---------------- l2norm of q (with 1/sqrt(DK)) and k, in-place ----------------
__global__ __launch_bounds__(256) void k_l2norm(float* __restrict__ mixed) {
    int tok = blockIdx.x, t = threadIdx.x;
    int vec = t >> 3, ln = t & 7;  // 32 vectors of 128, 8 lanes x 16 elems
    int off = (vec < 16) ? vec * 128 : 2048 + (vec - 16) * 128;
    float* p = mixed + (size_t)tok * N1 + off + ln * 16;
    f4_t x0 = ((f4_t*)p)[0], x1 = ((f4_t*)p)[1], x2 = ((f4_t*)p)[2], x3 = ((f4_t*)p)[3];
    float ss = 0.f;
#pragma unroll
    for (int i = 0; i < 4; i++) ss += x0[i]*x0[i] + x1[i]*x1[i] + x2[i]*x2[i] + x3[i]*x3[i];
    ss += __shfl_xor(ss, 1); ss += __shfl_xor(ss, 2); ss += __shfl_xor(ss, 4);
    float sc = 1.f / sqrtf(ss + 1e-6f);
    if (vec < 16) sc *= 0.08838834764831845f;  // DK^-0.5
#pragma unroll
    for (int i = 0; i < 4; i++) { x0[i]*=sc; x1[i]*=sc; x2[i]*=sc; x3[i]*=sc; }
    ((f4_t*)p)[0] = x0; ((f4_t*)p)[1] = x1; ((f4_t*)p)[2] = x2; ((f4_t*)p)[3] = x3;
}

// ---------------- gated delta-rule scan ----------------
// grid 512 = (b,h,colgroup): block = 16 cols x 16 k-segments of 8 floats.
// All state strictly in VGPRs (no arrays-of-vectors / unions -> no scratch).
__global__ __launch_bounds__(256, 2) void k_recur(const float* __restrict__ mixed,
                                                  const float* __restrict__ beta,
                                                  const float* __restrict__ eg,
                                                  float* __restrict__ o) {
    int blk = blockIdx.x;
    int cg = blk & 7, bh = blk >> 3;
    int h = bh & 31, b = bh >> 5;
    int hk = h >> 1;
    int t = threadIdx.x;
    int col = cg * 16 + (t >> 4);
    int seg = t & 15;
    const float* qbase = mixed + (size_t)(b * SEQ) * N1 + hk * 128 + seg * 8;
    const float* kbase = qbase + 2048;
    const float* vbase = mixed + (size_t)(b * SEQ) * N1 + 4096 + h * 128 + col;
    const float* gbase = eg + (size_t)(b * SEQ) * 32 + h;
    const float* bbase = beta + (size_t)(b * SEQ) * 32 + h;
    float* obase = o + (size_t)(b * SEQ) * 4096 + h * 128 + col;

    float S[8];
#pragma unroll
    for (int j = 0; j < 8; j++) S[j] = 0.f;

    f4_t q0 = ((const f4_t*)qbase)[0], q1 = ((const f4_t*)qbase)[1];
    f4_t k0 = ((const f4_t*)kbase)[0], k1 = ((const f4_t*)kbase)[1];
    float vv = vbase[0], egs = gbase[0], bts = bbase[0];

    for (int s = 0; s < SEQ; s++) {
        int s1 = (s + 1 < SEQ) ? s + 1 : SEQ - 1;
        const f4_t* qp = (const f4_t*)(qbase + (size_t)s1 * N1);
        const f4_t* kp = (const f4_t*)(kbase + (size_t)s1 * N1);
        f4_t q0n = qp[0], q1n = qp[1];
        f4_t k0n = kp[0], k1n = kp[1];
        float vvn = vbase[(size_t)s1 * N1];
        float egn = gbase[(size_t)s1 * 32];
        float btn = bbase[(size_t)s1 * 32];

        // pass 1: decay + k.S readout (two independent chains)
        float a0 = 0.f, a1 = 0.f;
        S[0] *= egs; a0 = fmaf(k0[0], S[0], a0);
        S[1] *= egs; a1 = fmaf(k0[1], S[1], a1);
        S[2] *= egs; a0 = fmaf(k0[2], S[2], a0);
        S[3] *= egs; a1 = fmaf(k0[3], S[3], a1);
        S[4] *= egs; a0 = fmaf(k1[0], S[4], a0);
        S[5] *= egs; a1 = fmaf(k1[1], S[5], a1);
        S[6] *= egs; a0 = fmaf(k1[2], S[6], a0);
        S[7] *= egs; a1 = fmaf(k1[3], S[7], a1);
        float acc = a0 + a1;
        acc += __shfl_xor(acc, 1); acc += __shfl_xor(acc, 2);
        acc += __shfl_xor(acc, 4); acc += __shfl_xor(acc, 8);
        float delta = (vv - acc) * bts;

        // pass 2: rank-1 write + q.S readout
        float o0 = 0.f, o1 = 0.f;
        S[0] = fmaf(k0[0], delta, S[0]); o0 = fmaf(q0[0], S[0], o0);
        S[1] = fmaf(k0[1], delta, S[1]); o1 = fmaf(q0[1], S[1], o1);
        S[2] = fmaf(k0[2], delta, S[2]); o0 = fmaf(q0[2], S[2], o0);
        S[3] = fmaf(k0[3], delta, S[3]); o1 = fmaf(q0[3], S[3], o1);
        S[4] = fmaf(k1[0], delta, S[4]); o0 = fmaf(q1[0], S[4], o0);
        S[5] = fmaf(k1[1], delta, S[5]); o1 = fmaf(q1[1], S[5], o1);
        S[6] = fmaf(k1[2], delta, S[6]); o0 = fmaf(q1[2], S[6], o0);
        S[7] = fmaf(k1[3], delta, S[7]); o1 = fmaf(q1[3], S[7], o1);
        float oa = o0 + o1;
        oa += __shfl_xor(oa, 1); oa += __shfl_xor(oa, 2);
        oa += __shfl_xor(oa, 4); oa += __shfl_xor(oa, 8);
        if (seg == 0) obase[(size_t)s * 4096] = oa;

        q0 = q0n; q1 = q1n; k0 = k0n; k1 = k1n;
        vv = vvn; egs = egn; bts = btn;
    }
}

// ---------------- gated RMSNorm -> bf16 ----------------
__global__ __launch_bounds__(256) void k_gnorm(const float* __restrict__ o,
                                               const float* __restrict__ mixed,
                                               const float* __restrict__ norm_w,
                                               unsigned short* __restrict__ on) {
    int tok = blockIdx.x, t = threadIdx.x;
    int hh = t >> 3, ln = t & 7;
    const f4_t* op = (const f4_t*)(o + (size_t)tok * 4096 + hh * 128 + ln * 16);
    const f4_t* zp = (const f4_t*)(mixed + (size_t)tok * N1 + 8192 + hh * 128 + ln * 16);
    float og[16];
    float ss = 0.f;
#pragma unroll
    for (int i = 0; i < 4; i++) {
        f4_t ov = op[i], zv = zp[i];
#pragma unroll
        for (int j = 0; j < 4; j++) {
            float z = zv[j];
            float g = ov[j] * (z / (1.f + expf(-z)));
            og[i * 4 + j] = g;
            ss += g * g;
        }
    }
    ss += __shfl_xor(ss, 1); ss += __shfl_xor(ss, 2); ss += __shfl_xor(ss, 4);
    float r = 1.f / sqrtf(ss * (1.f / 128.f) + 1e-6f);
    unsigned short* onp = on + (size_t)tok * 4096 + hh * 128 + ln * 16;
    u16x8 a, bb;
#pragma unroll
    for (int j = 0; j < 8; j++) a[j] = f2bf(og[j] * r * norm_w[ln * 16 + j]);
#pragma unroll
    for (int j = 0; j < 8; j++) bb[j] = f2bf(og[8 + j] * r * norm_w[ln * 16 + 8 + j]);
    ((u16x8*)onp)[0] = a;
    ((u16x8*)onp)[1] = bb;
}

extern "C" void kernel_launch(void* const* d_in, const int* in_sizes, int n_in,
                              void* d_out, int out_size, void* d_ws, size_t ws_size,
                              hipStream_t stream) {
    const float* hs      = (const float*)d_in[0];
    const float* conv_w  = (const float*)d_in[1];
    const float* w_qkv   = (const float*)d_in[2];
    const float* w_z     = (const float*)d_in[3];
    const float* w_b     = (const float*)d_in[4];
    const float* w_a     = (const float*)d_in[5];
    const float* w_out   = (const float*)d_in[6];
    const float* dt_bias = (const float*)d_in[7];
    const float* A_log   = (const float*)d_in[8];
    const float* norm_w  = (const float*)d_in[9];
    float* out = (float*)d_out;

    char* ws = (char*)d_ws;
    unsigned short* hs_bf = (unsigned short*)ws; ws += (size_t)NTOK * HIDDEN * 2;   // 8 MB
    unsigned short* w1t   = (unsigned short*)ws; ws += (size_t)N1 * HIDDEN * 2;     // 48 MB
    unsigned short* wot   = (unsigned short*)ws; ws += (size_t)HIDDEN * VAL_DIM * 2;// 16 MB
    float* mixed          = (float*)ws;          ws += (size_t)NTOK * N1 * 4;       // 96 MB
    float* beta           = (float*)ws;          ws += (size_t)NTOK * 32 * 4;
    float* eg             = (float*)ws;          ws += (size_t)NTOK * 32 * 4;
    float* halo           = (float*)ws;          ws += (size_t)2 * (NCH - 1) * 3 * 8192 * 4; // 6.1 MB
    float* o_buf          = (float*)ws;          ws += (size_t)NTOK * VAL_DIM * 4;  // 32 MB
    unsigned short* on_bf = (unsigned short*)ws; ws += (size_t)NTOK * VAL_DIM * 2;  // 16 MB
    // total ~223 MB

    k_cast_hs<<<dim3(NTOK * HIDDEN / 4 / 256), 256, 0, stream>>>(hs, hs_bf);
    k_trans_w1<<<dim3(N1 / 32, HIDDEN / 32), 256, 0, stream>>>(w_qkv, w_z, w1t);
    k_trans<<<dim3(HIDDEN / 32, VAL_DIM / 32), 256, 0, stream>>>(w_out, wot, VAL_DIM, HIDDEN);
    k_gemm_bt<<<dim3(NTOK / 128, N1 / 128), 256, 0, stream>>>(hs_bf, w1t, mixed, HIDDEN, N1);
    k_beta_g<<<dim3(NTOK), 256, 0, stream>>>(hs, w_b, w_a, dt_bias, A_log, beta, eg);
    k_halo<<<dim3(2 * (NCH - 1) * 3 * 8192 / 256), 256, 0, stream>>>(mixed, halo);
    k_conv<<<dim3(2 * NCH * 8192 / 256), 256, 0, stream>>>(mixed, conv_w, halo);
    k_l2norm<<<dim3(NTOK), 256, 0, stream>>>(mixed);
    k_recur<<<dim3(512), 256, 0, stream>>>(mixed, beta, eg, o_buf);
    k_gnorm<<<dim3(NTOK), 256, 0, stream>>>(o_buf, mixed, norm_w, on_bf);
    k_gemm_bt<<<dim3(NTOK / 128, HIDDEN / 128), 256, 0, stream>>>(on_bf, wot, out, VAL_DIM, HIDDEN);
}

// Round 3
// 916.931 us; speedup vs baseline: 1.4451x; 1.3481x over previous
//
#include <hip/hip_runtime.h>
#include <hip/hip_bf16.h>
#include <cstdint>

#define HIDDEN   2048
#define HV       32
#define HK       16
#define DK       128
#define DV       128
#define KEY_DIM  2048
#define VAL_DIM  4096
#define CONV_DIM 8192
#define NTOK     2048   // B*S
#define SEQ      1024
#define N1       12288  // 2*KEY_DIM + VAL_DIM (qkv ++ z fused GEMM)
#define C_CH     64     // delta-rule chunk length
#define NCHK     (SEQ / C_CH)

typedef __attribute__((ext_vector_type(4))) float f4_t;
typedef __attribute__((ext_vector_type(2))) float f2_t;
typedef __attribute__((ext_vector_type(8))) short bf8_t;
typedef __attribute__((ext_vector_type(16))) float f16acc;
typedef __attribute__((ext_vector_type(4))) unsigned short u16x4;
typedef __attribute__((ext_vector_type(8))) unsigned short u16x8;
typedef __attribute__((ext_vector_type(2))) uint32_t u32x2;
typedef __attribute__((ext_vector_type(4))) uint32_t u32x4;

__device__ __forceinline__ unsigned short f2bf(float f) {
    union { float f; uint32_t u; } a; a.f = f;
    uint32_t u = a.u;
    return (unsigned short)((u + 0x7fff + ((u >> 16) & 1)) >> 16);
}
__device__ __forceinline__ float bf2f(unsigned short h) {
    uint32_t u = ((uint32_t)h) << 16;
    union { uint32_t u; float f; } a; a.u = u;
    return a.f;
}
// 16B LDS fragment via two 8B loads (rows are 8B-aligned, strides chosen 2-way-max banks)
__device__ __forceinline__ bf8_t lds_frag(const unsigned short* p) {
    u32x2 a = *(const u32x2*)p;
    u32x2 b = *(const u32x2*)(p + 4);
    u32x4 w = {a[0], a[1], b[0], b[1]};
    return __builtin_bit_cast(bf8_t, w);
}

// ---------------- cast hs -> bf16 ----------------
__global__ __launch_bounds__(256) void k_cast_hs(const float* __restrict__ hs,
                                                 unsigned short* __restrict__ out) {
    int i = blockIdx.x * 256 + threadIdx.x;
    f4_t v = ((const f4_t*)hs)[i];
    u16x4 o;
    o[0] = f2bf(v[0]); o[1] = f2bf(v[1]); o[2] = f2bf(v[2]); o[3] = f2bf(v[3]);
    ((u16x4*)out)[i] = o;
}

// ---------------- transpose+cast: W1t[n][k] = {w_qkv|w_z}[k][n] ----------------
__global__ __launch_bounds__(256) void k_trans_w1(const float* __restrict__ w_qkv,
                                                  const float* __restrict__ w_z,
                                                  unsigned short* __restrict__ w1t) {
    __shared__ float tile[32][33];
    int tx = threadIdx.x & 31, ty = threadIdx.x >> 5;
    int n0 = blockIdx.x * 32, k0 = blockIdx.y * 32;
    int n = n0 + tx;
#pragma unroll
    for (int i = 0; i < 4; i++) {
        int k = k0 + ty + i * 8;
        float v = (n < CONV_DIM) ? w_qkv[(size_t)k * CONV_DIM + n]
                                 : w_z[(size_t)k * VAL_DIM + (n - CONV_DIM)];
        tile[ty + i * 8][tx] = v;
    }
    __syncthreads();
#pragma unroll
    for (int i = 0; i < 4; i++)
        w1t[(size_t)(n0 + ty + i * 8) * HIDDEN + k0 + tx] = f2bf(tile[tx][ty + i * 8]);
}

__global__ __launch_bounds__(256) void k_trans(const float* __restrict__ src,
                                               unsigned short* __restrict__ dst,
                                               int K, int N) {
    __shared__ float tile[32][33];
    int tx = threadIdx.x & 31, ty = threadIdx.x >> 5;
    int n0 = blockIdx.x * 32, k0 = blockIdx.y * 32;
#pragma unroll
    for (int i = 0; i < 4; i++)
        tile[ty + i * 8][tx] = src[(size_t)(k0 + ty + i * 8) * N + n0 + tx];
    __syncthreads();
#pragma unroll
    for (int i = 0; i < 4; i++)
        dst[(size_t)(n0 + ty + i * 8) * K + k0 + tx] = f2bf(tile[tx][ty + i * 8]);
}

// ---------------- bf16 MFMA GEMM:  C[M,N] = A[M,K] * B[N,K]^T ----------------
__global__ __launch_bounds__(256, 2) void k_gemm_bt(const unsigned short* __restrict__ A,
                                                    const unsigned short* __restrict__ B,
                                                    float* __restrict__ C, int K, int N) {
    __shared__ unsigned short lA[128 * 32];
    __shared__ unsigned short lB[128 * 32];
    int tid = threadIdx.x;
    int wave = tid >> 6, lane = tid & 63;
    int m0 = blockIdx.x * 128, n0 = blockIdx.y * 128;
    int wm = wave & 1, wn = wave >> 1;
    f4_t acc[4][4];
#pragma unroll
    for (int i = 0; i < 4; i++)
#pragma unroll
        for (int j = 0; j < 4; j++) acc[i][j] = (f4_t){0.f, 0.f, 0.f, 0.f};
    int srow = wave * 16 + (lane >> 2);
    int scol = (lane & 3) * 8;
    int quad = lane >> 4, lrow = lane & 15;

    for (int k0 = 0; k0 < K; k0 += 32) {
        const unsigned short* gA0 = A + (size_t)(m0 + srow) * K + k0 + scol;
        const unsigned short* gA1 = A + (size_t)(m0 + 64 + srow) * K + k0 + scol;
        const unsigned short* gB0 = B + (size_t)(n0 + srow) * K + k0 + scol;
        const unsigned short* gB1 = B + (size_t)(n0 + 64 + srow) * K + k0 + scol;
        __syncthreads();
        __builtin_amdgcn_global_load_lds((const __attribute__((address_space(1))) void*)gA0,
            (__attribute__((address_space(3))) void*)(&lA[wave * 512]), 16, 0, 0);
        __builtin_amdgcn_global_load_lds((const __attribute__((address_space(1))) void*)gA1,
            (__attribute__((address_space(3))) void*)(&lA[2048 + wave * 512]), 16, 0, 0);
        __builtin_amdgcn_global_load_lds((const __attribute__((address_space(1))) void*)gB0,
            (__attribute__((address_space(3))) void*)(&lB[wave * 512]), 16, 0, 0);
        __builtin_amdgcn_global_load_lds((const __attribute__((address_space(1))) void*)gB1,
            (__attribute__((address_space(3))) void*)(&lB[2048 + wave * 512]), 16, 0, 0);
        __syncthreads();
        bf8_t af[4], bfv[4];
#pragma unroll
        for (int i = 0; i < 4; i++) {
            af[i]  = *(const bf8_t*)&lA[(wm * 64 + i * 16 + lrow) * 32 + quad * 8];
            bfv[i] = *(const bf8_t*)&lB[(wn * 64 + i * 16 + lrow) * 32 + quad * 8];
        }
#pragma unroll
        for (int i = 0; i < 4; i++)
#pragma unroll
            for (int j = 0; j < 4; j++)
                acc[i][j] = __builtin_amdgcn_mfma_f32_16x16x32_bf16(af[i], bfv[j], acc[i][j], 0, 0, 0);
    }
#pragma unroll
    for (int i = 0; i < 4; i++) {
        int row_b = m0 + wm * 64 + i * 16 + quad * 4;
#pragma unroll
        for (int j = 0; j < 4; j++) {
            int col = n0 + wn * 64 + j * 16 + lrow;
#pragma unroll
            for (int r = 0; r < 4; r++)
                C[(size_t)(row_b + r) * N + col] = acc[i][j][r];
        }
    }
}

// ---------------- beta / raw log-decay g ----------------
__global__ __launch_bounds__(256) void k_beta_g(const float* __restrict__ hs,
                                                const float* __restrict__ w_b,
                                                const float* __restrict__ w_a,
                                                const float* __restrict__ dt_bias,
                                                const float* __restrict__ A_log,
                                                float* __restrict__ beta,
                                                float* __restrict__ gval) {
    __shared__ float row[HIDDEN];
    __shared__ float part[256];
    int tok = blockIdx.x, t = threadIdx.x;
    for (int i = t; i < HIDDEN; i += 256) row[i] = hs[(size_t)tok * HIDDEN + i];
    __syncthreads();
    int out = t & 63, qtr = t >> 6;
    const float* w = (out < 32) ? w_b : w_a;
    int h = out & 31;
    float acc = 0.f;
    for (int k = qtr * 512; k < qtr * 512 + 512; k++) acc += row[k] * w[k * 32 + h];
    part[t] = acc;
    __syncthreads();
    if (t < 64) {
        float s = part[t] + part[t + 64] + part[t + 128] + part[t + 192];
        if (t < 32) {
            beta[tok * 32 + t] = 1.f / (1.f + expf(-s));
        } else {
            int hh = t - 32;
            float x = s + dt_bias[hh];
            float sp = (x > 20.f) ? x : log1pf(expf(x));
            gval[tok * 32 + hh] = -expf(A_log[hh]) * sp;   // log-decay (<= 0)
        }
    }
}

// ---------------- conv halo + chunked in-place conv ----------------
#define CCH 32
#define NCHC (SEQ / CCH)
__global__ __launch_bounds__(256) void k_halo(const float* __restrict__ mixed,
                                              float* __restrict__ halo) {
    int id = blockIdx.x * 256 + threadIdx.x;
    int c = id & 8191;
    int r = id >> 13;
    int tap = r % 3;
    int ck = (r / 3) % (NCHC - 1);
    int b = r / (3 * (NCHC - 1));
    int s = (ck + 1) * CCH - 1 - tap;
    halo[id] = mixed[(size_t)(b * SEQ + s) * N1 + c];
}

__global__ __launch_bounds__(256) void k_conv(float* __restrict__ mixed,
                                              const float* __restrict__ cw,
                                              const float* __restrict__ halo) {
    int id = blockIdx.x * 256 + threadIdx.x;
    int c = id & 8191;
    int r = id >> 13;
    int chunk = r & (NCHC - 1), b = r >> 5;
    int s0 = chunk * CCH;
    float w0 = cw[c * 4 + 0], w1 = cw[c * 4 + 1], w2 = cw[c * 4 + 2], w3 = cw[c * 4 + 3];
    float xm1, xm2, xm3;
    if (chunk == 0) {
        xm1 = xm2 = xm3 = 0.f;
    } else {
        const float* hp = halo + (size_t)(b * (NCHC - 1) + chunk - 1) * 3 * 8192;
        xm1 = hp[0 * 8192 + c]; xm2 = hp[1 * 8192 + c]; xm3 = hp[2 * 8192 + c];
    }
    float* col = mixed + (size_t)(b * SEQ + s0) * N1 + c;
#pragma unroll
    for (int s = 0; s < CCH; s++) {
        float x = col[(size_t)s * N1];
        float y = w3 * x + w2 * xm1 + w1 * xm2 + w0 * xm3;
        y = y / (1.f + expf(-y));
        col[(size_t)s * N1] = y;
        xm3 = xm2; xm2 = xm1; xm1 = x;
    }
}

// ---------------- l2norm of q (with 1/sqrt(DK)) and k, in-place ----------------
__global__ __launch_bounds__(256) void k_l2norm(float* __restrict__ mixed) {
    int tok = blockIdx.x, t = threadIdx.x;
    int vec = t >> 3, ln = t & 7;
    int off = (vec < 16) ? vec * 128 : 2048 + (vec - 16) * 128;
    float* p = mixed + (size_t)tok * N1 + off + ln * 16;
    f4_t x0 = ((f4_t*)p)[0], x1 = ((f4_t*)p)[1], x2 = ((f4_t*)p)[2], x3 = ((f4_t*)p)[3];
    float ss = 0.f;
#pragma unroll
    for (int i = 0; i < 4; i++) ss += x0[i]*x0[i] + x1[i]*x1[i] + x2[i]*x2[i] + x3[i]*x3[i];
    ss += __shfl_xor(ss, 1); ss += __shfl_xor(ss, 2); ss += __shfl_xor(ss, 4);
    float sc = 1.f / sqrtf(ss + 1e-6f);
    if (vec < 16) sc *= 0.08838834764831845f;
#pragma unroll
    for (int i = 0; i < 4; i++) { x0[i]*=sc; x1[i]*=sc; x2[i]*=sc; x3[i]*=sc; }
    ((f4_t*)p)[0] = x0; ((f4_t*)p)[1] = x1; ((f4_t*)p)[2] = x2; ((f4_t*)p)[3] = x3;
}

// ---------------- chunked gated delta rule ----------------
// grid 256 = (b, h, vs): 4 waves, state slice S[128dk, 32dv] in MFMA accumulators
// (wave w owns dk rows 32w..32w+31). Chunk C=64:
//   M = beta_i*(K K^T)*exp(Gi-Gj) (j<i);  (I+M) Delta = beta*(V - Lam*K S0)
//   O = diag(Lam) Q S0 + P Delta,  P = (Q K^T)*exp(Gi-Gj) (j<=i)
//   S <- Lam_C S + Kbar^T Delta,   Kbar_i = exp(G_C - G_i) k_i
__global__ __launch_bounds__(256, 1) void k_chunk(const float* __restrict__ mixed,
                                                  const float* __restrict__ beta,
                                                  const float* __restrict__ gval,
                                                  float* __restrict__ o) {
    __shared__ unsigned short lK[64 * 132];   // K chunk bf16 (rows, stride 132)
    __shared__ unsigned short lQ[64 * 132];   // Q chunk bf16
    __shared__ unsigned short lKt[128 * 68];  // Kbar^T bf16 [dk][i]
    __shared__ unsigned short lSt[32 * 132];  // S^T bf16 [v][dk]
    __shared__ unsigned short lP[64 * 68];    // P bf16 [i][j]
    __shared__ unsigned short lDt[32 * 68];   // Delta^T bf16 [v][i]
    __shared__ float lM[64 * 66];             // M fp32 (strict lower used)
    __shared__ float lR[64 * 34];             // W raw -> R -> solved rows
    __shared__ float lV[64 * 34];             // V chunk fp32
    __shared__ float lDf[64 * 34];            // Delta fp32 [i][v]
    __shared__ float lG[64], lLam[64], lBeta[64], lKsc[64];

    int blk = blockIdx.x;
    int vs = blk & 3, h = (blk >> 2) & 31, b = blk >> 7;
    int hk = h >> 1;
    int t = threadIdx.x;
    int wave = t >> 6, lane = t & 63;
    int half = lane >> 5, lm = lane & 31;

    for (int i = t; i < 32 * 132; i += 256) lSt[i] = 0;
    f16acc sacc;
#pragma unroll
    for (int r = 0; r < 16; r++) sacc[r] = 0.f;
    __syncthreads();

    const float* qptr = mixed + (size_t)(b * SEQ) * N1 + hk * 128;
    const float* kptr = qptr + 2048;
    const float* vptr = mixed + (size_t)(b * SEQ) * N1 + 4096 + h * 128 + vs * 32;

    for (int c = 0; c < NCHK; c++) {
        int s0 = c * C_CH;
        // ---- stage K,Q,V + g/beta scan ----
        {
            int i = t >> 2, c0 = (t & 3) * 32;
            const float* kr = kptr + (size_t)(s0 + i) * N1 + c0;
            const float* qr = qptr + (size_t)(s0 + i) * N1 + c0;
            unsigned short* dK = &lK[i * 132 + c0];
            unsigned short* dQ = &lQ[i * 132 + c0];
#pragma unroll
            for (int u = 0; u < 8; u++) {
                f4_t kv = ((const f4_t*)kr)[u];
                f4_t qv = ((const f4_t*)qr)[u];
                u16x4 ks, qs;
#pragma unroll
                for (int e = 0; e < 4; e++) { ks[e] = f2bf(kv[e]); qs[e] = f2bf(qv[e]); }
                *(u16x4*)(dK + u * 4) = ks;
                *(u16x4*)(dQ + u * 4) = qs;
            }
            const float* vr = vptr + (size_t)(s0 + i) * N1 + (t & 3) * 8;
            f4_t v0 = ((const f4_t*)vr)[0], v1 = ((const f4_t*)vr)[1];
            float* dV = &lV[i * 34 + (t & 3) * 8];
            f2_t p0 = {v0[0], v0[1]}, p1 = {v0[2], v0[3]}, p2 = {v1[0], v1[1]}, p3 = {v1[2], v1[3]};
            ((f2_t*)dV)[0] = p0; ((f2_t*)dV)[1] = p1; ((f2_t*)dV)[2] = p2; ((f2_t*)dV)[3] = p3;
            if (t < 64) {
                float gv = gval[(size_t)(b * SEQ + s0 + t) * 32 + h];
                float bv = beta[(size_t)(b * SEQ + s0 + t) * 32 + h];
                float x = gv;
#pragma unroll
                for (int d = 1; d < 64; d <<= 1) {
                    float y = __shfl_up(x, d);
                    if (t >= d) x += y;
                }
                float Gc = __shfl(x, 63);
                lG[t] = x; lLam[t] = expf(x); lBeta[t] = bv; lKsc[t] = expf(Gc - x);
            }
        }
        __syncthreads();
        // ---- transpose: lKt[d][i] = Kbar^T ----
        {
            int d = t >> 1, i0 = (t & 1) * 32;
#pragma unroll
            for (int ii = 0; ii < 32; ii++) {
                int i = i0 + ii;
                lKt[d * 68 + i] = f2bf(bf2f(lK[i * 132 + d]) * lKsc[i]);
            }
        }
        __syncthreads();
        // ---- MFMA phase A: M (3 tiles), P (3 tiles) + elementwise ----
        for (int job = wave; job < 6; job += 4) {
            int isP = job >= 3 ? 1 : 0;
            int jj = job - (isP ? 3 : 0);
            int ib = (jj == 0) ? 0 : 1;
            int jb = (jj == 2) ? 1 : 0;
            const unsigned short* Ab = isP ? lQ : lK;
            f16acc acc;
#pragma unroll
            for (int r = 0; r < 16; r++) acc[r] = 0.f;
            int arow = ib * 32 + lm, brow = jb * 32 + lm;
#pragma unroll
            for (int k0 = 0; k0 < 128; k0 += 16) {
                bf8_t a = lds_frag(&Ab[arow * 132 + k0 + half * 8]);
                bf8_t bb = lds_frag(&lK[brow * 132 + k0 + half * 8]);
                acc = __builtin_amdgcn_mfma_f32_32x32x16_bf16(a, bb, acc, 0, 0, 0);
            }
            int j = jb * 32 + lm;
            float Gj = lG[j];
#pragma unroll
            for (int r = 0; r < 16; r++) {
                int ml = (r & 3) + 8 * (r >> 2) + 4 * half;
                int i = ib * 32 + ml;
                float f = expf(lG[i] - Gj);
                if (isP) {
                    lP[i * 68 + j] = f2bf((j <= i) ? acc[r] * f : 0.f);
                } else {
                    if (j < i) lM[i * 66 + j] = acc[r] * lBeta[i] * f;
                }
            }
        }
        // zero P upper-right tile (rows 0..31, cols 32..63)
#pragma unroll
        for (int u = 0; u < 4; u++) {
            int e = t * 4 + u;
            lP[(e >> 5) * 68 + 32 + (e & 31)] = 0;
        }
        // ---- MFMA: W raw (waves 0,1) / O_inter raw (waves 2,3) using S^T ----
        f16acc wacc;
#pragma unroll
        for (int r = 0; r < 16; r++) wacc[r] = 0.f;
        {
            int ib = wave & 1;
            const unsigned short* Ab = (wave < 2) ? lK : lQ;
            int arow = ib * 32 + lm;
#pragma unroll
            for (int k0 = 0; k0 < 128; k0 += 16) {
                bf8_t a = lds_frag(&Ab[arow * 132 + k0 + half * 8]);
                bf8_t bb = lds_frag(&lSt[lm * 132 + k0 + half * 8]);
                wacc = __builtin_amdgcn_mfma_f32_32x32x16_bf16(a, bb, wacc, 0, 0, 0);
            }
            if (wave < 2) {
#pragma unroll
                for (int r = 0; r < 16; r++) {
                    int ml = (r & 3) + 8 * (r >> 2) + 4 * half;
                    lR[(ib * 32 + ml) * 34 + lm] = wacc[r];
                }
            }
        }
        __syncthreads();
        // ---- R = beta*(V - Lam*Wraw) ----
#pragma unroll
        for (int u = 0; u < 8; u++) {
            int e = t * 8 + u;
            int i = e >> 5, v = e & 31;
            lR[i * 34 + v] = lBeta[i] * (lV[i * 34 + v] - lLam[i] * lR[i * 34 + v]);
        }
        __syncthreads();
        // ---- blocked forward substitution: (I+M) Delta = R ----
        for (int sb = 0; sb < 4; sb++) {
            if (sb > 0) {
                int i = 16 * sb + (t & 15), v = t >> 4;
                float a0 = lR[i * 34 + v], a1 = lR[i * 34 + v + 16];
                for (int j = 0; j < 16 * sb; j++) {
                    float m = lM[i * 66 + j];
                    a0 -= m * lDf[j * 34 + v];
                    a1 -= m * lDf[j * 34 + v + 16];
                }
                lR[i * 34 + v] = a0; lR[i * 34 + v + 16] = a1;
                __syncthreads();
            }
            if (t < 32) {
                int v = t;
                float dd[16];
                dd[0] = lR[(16 * sb) * 34 + v];
#pragma unroll
                for (int il = 1; il < 16; il++) {
                    float acc = lR[(16 * sb + il) * 34 + v];
#pragma unroll
                    for (int jl = 0; jl < il; jl++)
                        acc -= lM[(16 * sb + il) * 66 + 16 * sb + jl] * dd[jl];
                    dd[il] = acc;
                }
#pragma unroll
                for (int il = 0; il < 16; il++) {
                    lDf[(16 * sb + il) * 34 + v] = dd[il];
                    lDt[v * 68 + 16 * sb + il] = f2bf(dd[il]);
                }
            }
            __syncthreads();
        }
        // ---- tail: O = diag(Lam)*Oraw + P*Delta (waves 2,3); S update (all) ----
        float LamC = lLam[63];
        if (wave >= 2) {
            int ib = wave & 1;
#pragma unroll
            for (int r = 0; r < 16; r++) {
                int ml = (r & 3) + 8 * (r >> 2) + 4 * half;
                wacc[r] *= lLam[ib * 32 + ml];
            }
#pragma unroll
            for (int j0 = 0; j0 < 64; j0 += 16) {
                bf8_t a = lds_frag(&lP[(ib * 32 + lm) * 68 + j0 + half * 8]);
                bf8_t bb = lds_frag(&lDt[lm * 68 + j0 + half * 8]);
                wacc = __builtin_amdgcn_mfma_f32_32x32x16_bf16(a, bb, wacc, 0, 0, 0);
            }
#pragma unroll
            for (int r = 0; r < 16; r++) {
                int ml = (r & 3) + 8 * (r >> 2) + 4 * half;
                o[(size_t)(b * SEQ + s0 + ib * 32 + ml) * 4096 + h * 128 + vs * 32 + lm] = wacc[r];
            }
        }
#pragma unroll
        for (int r = 0; r < 16; r++) sacc[r] *= LamC;
#pragma unroll
        for (int i0 = 0; i0 < 64; i0 += 16) {
            bf8_t a = lds_frag(&lKt[(32 * wave + lm) * 68 + i0 + half * 8]);
            bf8_t bb = lds_frag(&lDt[lm * 68 + i0 + half * 8]);
            sacc = __builtin_amdgcn_mfma_f32_32x32x16_bf16(a, bb, sacc, 0, 0, 0);
        }
#pragma unroll
        for (int r = 0; r < 16; r++) {
            int ml = (r & 3) + 8 * (r >> 2) + 4 * half;
            lSt[lm * 132 + 32 * wave + ml] = f2bf(sacc[r]);
        }
        __syncthreads();
    }
}

// ---------------- gated RMSNorm -> bf16 ----------------
__global__ __launch_bounds__(256) void k_gnorm(const float* __restrict__ o,
                                               const float* __restrict__ mixed,
                                               const float* __restrict__ norm_w,
                                               unsigned short* __restrict__ on) {
    int tok = blockIdx.x, t = threadIdx.x;
    int hh = t >> 3, ln = t & 7;
    const f4_t* op = (const f4_t*)(o + (size_t)tok * 4096 + hh * 128 + ln * 16);
    const f4_t* zp = (const f4_t*)(mixed + (size_t)tok * N1 + 8192 + hh * 128 + ln * 16);
    float og[16];
    float ss = 0.f;
#pragma unroll
    for (int i = 0; i < 4; i++) {
        f4_t ov = op[i], zv = zp[i];
#pragma unroll
        for (int j = 0; j < 4; j++) {
            float z = zv[j];
            float g = ov[j] * (z / (1.f + expf(-z)));
            og[i * 4 + j] = g;
            ss += g * g;
        }
    }
    ss += __shfl_xor(ss, 1); ss += __shfl_xor(ss, 2); ss += __shfl_xor(ss, 4);
    float r = 1.f / sqrtf(ss * (1.f / 128.f) + 1e-6f);
    unsigned short* onp = on + (size_t)tok * 4096 + hh * 128 + ln * 16;
    u16x8 a, bb;
#pragma unroll
    for (int j = 0; j < 8; j++) a[j] = f2bf(og[j] * r * norm_w[ln * 16 + j]);
#pragma unroll
    for (int j = 0; j < 8; j++) bb[j] = f2bf(og[8 + j] * r * norm_w[ln * 16 + 8 + j]);
    ((u16x8*)onp)[0] = a;
    ((u16x8*)onp)[1] = bb;
}

extern "C" void kernel_launch(void* const* d_in, const int* in_sizes, int n_in,
                              void* d_out, int out_size, void* d_ws, size_t ws_size,
                              hipStream_t stream) {
    const float* hs      = (const float*)d_in[0];
    const float* conv_w  = (const float*)d_in[1];
    const float* w_qkv   = (const float*)d_in[2];
    const float* w_z     = (const float*)d_in[3];
    const float* w_b     = (const float*)d_in[4];
    const float* w_a     = (const float*)d_in[5];
    const float* w_out   = (const float*)d_in[6];
    const float* dt_bias = (const float*)d_in[7];
    const float* A_log   = (const float*)d_in[8];
    const float* norm_w  = (const float*)d_in[9];
    float* out = (float*)d_out;

    char* ws = (char*)d_ws;
    unsigned short* hs_bf = (unsigned short*)ws; ws += (size_t)NTOK * HIDDEN * 2;
    unsigned short* w1t   = (unsigned short*)ws; ws += (size_t)N1 * HIDDEN * 2;
    unsigned short* wot   = (unsigned short*)ws; ws += (size_t)HIDDEN * VAL_DIM * 2;
    float* mixed          = (float*)ws;          ws += (size_t)NTOK * N1 * 4;
    float* beta           = (float*)ws;          ws += (size_t)NTOK * 32 * 4;
    float* gval           = (float*)ws;          ws += (size_t)NTOK * 32 * 4;
    float* halo           = (float*)ws;          ws += (size_t)2 * (NCHC - 1) * 3 * 8192 * 4;
    float* o_buf          = (float*)ws;          ws += (size_t)NTOK * VAL_DIM * 4;
    unsigned short* on_bf = (unsigned short*)ws; ws += (size_t)NTOK * VAL_DIM * 2;

    k_cast_hs<<<dim3(NTOK * HIDDEN / 4 / 256), 256, 0, stream>>>(hs, hs_bf);
    k_trans_w1<<<dim3(N1 / 32, HIDDEN / 32), 256, 0, stream>>>(w_qkv, w_z, w1t);
    k_trans<<<dim3(HIDDEN / 32, VAL_DIM / 32), 256, 0, stream>>>(w_out, wot, VAL_DIM, HIDDEN);
    k_gemm_bt<<<dim3(NTOK / 128, N1 / 128), 256, 0, stream>>>(hs_bf, w1t, mixed, HIDDEN, N1);
    k_beta_g<<<dim3(NTOK), 256, 0, stream>>>(hs, w_b, w_a, dt_bias, A_log, beta, gval);
    k_halo<<<dim3(2 * (NCHC - 1) * 3 * 8192 / 256), 256, 0, stream>>>(mixed, halo);
    k_conv<<<dim3(2 * NCHC * 8192 / 256), 256, 0, stream>>>(mixed, conv_w, halo);
    k_l2norm<<<dim3(NTOK), 256, 0, stream>>>(mixed);
    k_chunk<<<dim3(256), 256, 0, stream>>>(mixed, beta, gval, o_buf);
    k_gnorm<<<dim3(NTOK), 256, 0, stream>>>(o_buf, mixed, norm_w, on_bf);
    k_gemm_bt<<<dim3(NTOK / 128, HIDDEN / 128), 256, 0, stream>>>(on_bf, wot, out, VAL_DIM, HIDDEN);
}